// Round 16
// baseline (650.325 us; speedup 1.0000x reference)
//
#include <hip/hip_runtime.h>
#include <hip/hip_bf16.h>

typedef __attribute__((ext_vector_type(4))) int i32x4;
typedef __attribute__((ext_vector_type(8))) int i32x8;
typedef __attribute__((ext_vector_type(4))) float f32x4;

// exact floor(log2(x)) for x > 0 (handles subnormals)
__device__ __forceinline__ int flog2(float x) {
  unsigned u = __float_as_uint(x);
  int e = (int)((u >> 23) & 255u);
  if (e) return e - 127;
  unsigned m = u & 0x7fffffu;
  return (31 - __clz(m)) - 149;
}

// exact 2^e for e in [-252, 254]
__device__ __forceinline__ float exp2i(int e) {
  int e1 = e >> 1, e2 = e - e1;
  return __uint_as_float((unsigned)(e1 + 127) << 23) *
         __uint_as_float((unsigned)(e2 + 127) << 23);
}

// quantize y (already divided by shared scale) to e2m<MFRAC>, round-half-even, saturate
template <int MFRAC>
__device__ __forceinline__ float qelem(float y, float maxn) {
  float ay = fabsf(y);
  int e = (ay == 0.f) ? 0 : flog2(ay);
  if (e < 0) e = 0;  // min_exp = 0 for ebits=2
  float r = rintf(y * exp2i(MFRAC - e)) * exp2i(e - MFRAC);
  return fminf(fmaxf(r, -maxn), maxn);
}

// general RNE fp32 -> OCP e4m3 encode (|v| <= 448; exact on our folded value grid)
__device__ __forceinline__ unsigned char enc_rne(float v) {
  unsigned u = __float_as_uint(v);
  unsigned s = u >> 31;
  float a = fabsf(v);
  if (a == 0.f) return (unsigned char)(s << 7);
  int e = flog2(a);
  if (e < -6) e = -6;                      // subnormal regime
  int qi = (int)rintf(a * exp2i(3 - e));   // RNE to 3-frac-bit grid -> [0,16]
  if (qi == 0) return (unsigned char)(s << 7);
  if (qi == 16) { qi = 8; e += 1; }
  unsigned exf, m;
  if (qi < 8) { exf = 0u; m = (unsigned)qi; }          // e == -6 subnormal
  else { exf = (unsigned)(e + 7); m = (unsigned)(qi - 8); }
  return (unsigned char)((s << 7) | (exf << 3) | m);
}

// fragment-page swizzle: byte address of element (row, col-in-K) in a tensor stored
// as 2KB pages per (16-row-block x 128-K-block); pa = K/128 pages per row-block.
//   byte(j*1024 + l*16 + b) = elem(row = rb*16 + (l&15), k = kb*128 + (l>>4)*32 + j*16 + b)
__device__ __forceinline__ size_t swz(int row, int col, int pa) {
  return ((size_t)((row >> 4) * pa + (col >> 7))) * 2048
       + (size_t)(((col >> 4) & 1) * 1024
       + ((row & 15) + ((col >> 5) & 3) * 16) * 16
       + (col & 15));
}

// ------ MX quantization with exponent folding -> fragment-page-swizzled e4m3 bytes ---
template <int MFRAC, int EMAX>
__global__ void quant_fold(const float* __restrict__ in, unsigned char* __restrict__ out,
                           long n4, float maxn, int se0, int kshift, int kmask, int pa) {
  long i = (long)blockIdx.x * blockDim.x + threadIdx.x;
  long stride = (long)gridDim.x * blockDim.x;
  for (; i < n4; i += stride) {
    float4 v = reinterpret_cast<const float4*>(in)[i];
    float am = fmaxf(fmaxf(fabsf(v.x), fabsf(v.y)), fmaxf(fabsf(v.z), fabsf(v.w)));
    am = fmaxf(am, __shfl_xor(am, 1));
    am = fmaxf(am, __shfl_xor(am, 2));
    am = fmaxf(am, __shfl_xor(am, 4));
    int se = ((am == 0.f) ? 0 : flog2(am)) - EMAX;
    se = se < -127 ? -127 : (se > 127 ? 127 : se);
    float inv = exp2i(-se), f = exp2i(se - se0);
    unsigned o = (unsigned)enc_rne(qelem<MFRAC>(v.x * inv, maxn) * f)
               | ((unsigned)enc_rne(qelem<MFRAC>(v.y * inv, maxn) * f) << 8)
               | ((unsigned)enc_rne(qelem<MFRAC>(v.z * inv, maxn) * f) << 16)
               | ((unsigned)enc_rne(qelem<MFRAC>(v.w * inv, maxn) * f) << 24);
    int row = (int)(i >> kshift);
    int kq = ((int)i & kmask) * 4;           // kq % 16 in {0,4,8,12}: 4B stays in-piece
    reinterpret_cast<unsigned*>(out)[swz(row, kq, pa) >> 2] = o;
  }
}

// load one MFMA fragment (lane's 32B) directly from a global fragment page
__device__ __forceinline__ i32x8 gfrag(const unsigned char* page, int l16) {
  i32x4 lo = *reinterpret_cast<const i32x4*>(page + l16);
  i32x4 hi = *reinterpret_cast<const i32x4*>(page + 1024 + l16);
  i32x8 r;
  r[0] = lo[0]; r[1] = lo[1]; r[2] = lo[2]; r[3] = lo[3];
  r[4] = hi[0]; r[5] = hi[1]; r[6] = hi[2]; r[7] = hi[3];
  return r;
}

// ----- fp8 GEMM, 16x16x128 MFMA, NO LDS / NO BARRIERS, register double-buffer ------
// + bijective XCD swizzle: each XCD owns a contiguous (bx-outer, by-inner) chunk so
// its B-slice stays L2-resident and the A strip stays L2-hot.
// All HW scale bytes = 1.0 (0x7f7f7f7f): convention-immune, full MX instruction rate.
// EPI=0: fp32 out (+ ks split via Cf/Cf2); EPI=1: up-fused (fp32 gate in, fp8 out).
template <int EPI>
__global__ __launch_bounds__(256) void mx_gemm(
    const unsigned char* __restrict__ A, int pa,
    const unsigned char* __restrict__ B, int pb,
    float* __restrict__ Cf, float* __restrict__ Cf2,
    const float* __restrict__ gate, unsigned char* __restrict__ C8,
    int W, int K, int ldC, int c0, float fac, int se0out, int nby, int nks) {
  const int t = threadIdx.x, l = t & 63, w = t >> 6;
  const int wr = w >> 1, wc = w & 1;          // 2x2 wave grid; wave tile 64x64
  const int lr16 = l & 15, lg16 = l >> 4;
  const int l16 = l * 16;
  // XCD-bijective swizzle (T1, correct form): n -> (bx, by, ks)
  const int n = (int)blockIdx.x;
  int bx, byks;
  const int slots = nby * nks;                 // by-ks slots total
  if ((slots & 7) == 0) {
    const int loc = slots >> 3;                // slots per XCD
    const int xcd = n & 7, idx = n >> 3;
    bx = idx / loc;                            // A strip: outer (stays L2-hot)
    byks = xcd * loc + (idx - bx * loc);       // B slice: inner, contiguous per XCD
  } else {
    bx = n & 31; byks = n >> 5;
  }
  const int by = byks % nby, ks = byks / nby;
  const int rowA = bx * 128, rowB = by * 128;
  const int kbs = ks * (K >> 7);               // page offset for K-split
  const int SCL = 0x7f7f7f7f;  // e8m0 1.0 in every byte: scale path is a no-op

  f32x4 acc[4][4];
#pragma unroll
  for (int i = 0; i < 4; ++i)
#pragma unroll
    for (int j = 0; j < 4; ++j) acc[i][j] = (f32x4)(0.f);

  const unsigned char* pApg[4];
  const unsigned char* pBpg[4];
#pragma unroll
  for (int m = 0; m < 4; ++m) {
    pApg[m] = A + ((size_t)((rowA >> 4) + wr * 4 + m) * pa + kbs) * 2048;
    pBpg[m] = B + ((size_t)((rowB >> 4) + wc * 4 + m) * pb + kbs) * 2048;
  }

  i32x8 a0[4], b0[4], a1[4], b1[4];
  auto loadT = [&](i32x8* da, i32x8* db) {  // issue 16 b128 loads, advance pointers
#pragma unroll
    for (int m = 0; m < 4; ++m) { da[m] = gfrag(pApg[m], l16); pApg[m] += 2048; }
#pragma unroll
    for (int m = 0; m < 4; ++m) { db[m] = gfrag(pBpg[m], l16); pBpg[m] += 2048; }
  };
  auto mfma16 = [&](const i32x8* a, const i32x8* b) {
#pragma unroll
    for (int m = 0; m < 4; ++m)
#pragma unroll
      for (int nn = 0; nn < 4; ++nn)
        acc[m][nn] = __builtin_amdgcn_mfma_scale_f32_16x16x128_f8f6f4(
            a[m], b[nn], acc[m][nn], 0, 0, 0, SCL, 0, SCL);
  };

  const int nt = K >> 7;  // 16 (gate/up) or 32 (down halves): even
  // register double-buffer: next tile's loads issue BEFORE current tile's MFMAs;
  // no barriers/LDS -> loads stay in flight under the MFMA phase.
  loadT(a0, b0);
  for (int kb = 0; kb + 2 < nt; kb += 2) {
    loadT(a1, b1);
    mfma16(a0, b0);
    loadT(a0, b0);
    mfma16(a1, b1);
  }
  loadT(a1, b1);
  mfma16(a0, b0);
  mfma16(a1, b1);

  // 16x16 C/D layout: col = lane&15, row = (lane>>4)*4 + reg  (m89-verified)
  if (EPI == 0) {
    float* D = ks ? Cf2 : Cf;
#pragma unroll
    for (int m = 0; m < 4; ++m)
#pragma unroll
      for (int nn = 0; nn < 4; ++nn)
#pragma unroll
        for (int r = 0; r < 4; ++r) {
          int row = rowA + wr * 64 + m * 16 + lg16 * 4 + r;
          int col = rowB + wc * 64 + nn * 16 + lr16;
          D[(size_t)row * ldC + c0 + col] = acc[m][nn][r] * fac;
        }
  } else {
    const int pao = ldC >> 7;  // output pages per row-block
#pragma unroll
    for (int m = 0; m < 4; ++m)
#pragma unroll
      for (int p = 0; p < 2; ++p)
#pragma unroll
        for (int r = 0; r < 4; ++r) {
          int row = rowA + wr * 64 + m * 16 + lg16 * 4 + r;
          int col = rowB + wc * 64 + p * 32 + lr16;  // chunk-local column in [0, W)
          float u0 = acc[m][2 * p][r] * fac;
          float u1 = acc[m][2 * p + 1][r] * fac;
          float g0 = gate[(size_t)row * W + col];
          float g1 = gate[(size_t)row * W + col + 16];
          float v0 = u0 * (g0 / (1.f + expf(-g0)));
          float v1 = u1 * (g1 / (1.f + expf(-g1)));
          float am = fmaxf(fabsf(v0), fabsf(v1));
          am = fmaxf(am, __shfl_xor(am, 1));
          am = fmaxf(am, __shfl_xor(am, 2));
          am = fmaxf(am, __shfl_xor(am, 4));
          am = fmaxf(am, __shfl_xor(am, 8));
          int se = ((am == 0.f) ? 0 : flog2(am)) - 2;
          se = se < -127 ? -127 : (se > 127 ? 127 : se);
          float f = exp2i(-se), fo = exp2i(se - se0out);
          C8[swz(row, c0 + col, pao)] = enc_rne(qelem<3>(v0 * f, 7.5f) * fo);
          C8[swz(row, c0 + col + 16, pao)] = enc_rne(qelem<3>(v1 * f, 7.5f) * fo);
        }
  }
}

__global__ void add_f32(float* __restrict__ out, const float* __restrict__ part, long n4) {
  long i = (long)blockIdx.x * blockDim.x + threadIdx.x;
  long stride = (long)gridDim.x * blockDim.x;
  for (; i < n4; i += stride) {
    float4 a = reinterpret_cast<float4*>(out)[i];
    float4 b = reinterpret_cast<const float4*>(part)[i];
    a.x += b.x; a.y += b.y; a.z += b.z; a.w += b.w;
    reinterpret_cast<float4*>(out)[i] = a;
  }
}

extern "C" void kernel_launch(void* const* d_in, const int* in_sizes, int n_in,
                              void* d_out, int out_size, void* d_ws, size_t ws_size,
                              hipStream_t stream) {
  const float* x = (const float*)d_in[0];
  const float* wg = (const float*)d_in[1];
  const float* wu = (const float*)d_in[2];
  const float* wd = (const float*)d_in[3];
  float* out = (float*)d_out;

  const int S = 4096, H = 2048, I = 8192;

  // per-tensor fold baselines: exact while block se in [se0-6, se0+5]
  const int SE0X = -1, SE0W = -7, SE0I = -2;
  const float FAC_GU = 0.00390625f;     // 2^(SE0X + SE0W) = 2^-8
  const float FAC_DN = 0.001953125f;    // 2^(SE0I + SE0W) = 2^-9

  unsigned char* p = (unsigned char*)d_ws;
  unsigned char* xq8 = p;  p += (size_t)S * H;   //  8.4 MB (swizzled pages)
  unsigned char* wgq8 = p; p += (size_t)I * H;   // 16.8 MB
  unsigned char* wuq8 = p; p += (size_t)I * H;   // 16.8 MB
  unsigned char* wdq8 = p; p += (size_t)H * I;   // 16.8 MB
  unsigned char* iq8 = p;  p += (size_t)S * I;   // 33.6 MB
  size_t base_bytes = (size_t)(p - (unsigned char*)d_ws);  // ~92 MB
  float* gatef = (float*)p;          // chunked fp32 gate buffer (exact; feeds requant)
  float* pf = (float*)p;             // down K-split partial (reuses dead gatef)

  // quantize -> fragment-page-swizzled e4m3
  quant_fold<3, 2><<<2048, 256, 0, stream>>>(x, xq8, (long)S * H / 4, 7.5f, SE0X,
                                             9, 511, H / 128);    // K=2048
  quant_fold<1, 2><<<2048, 256, 0, stream>>>(wg, wgq8, (long)I * H / 4, 6.0f, SE0W,
                                             9, 511, H / 128);
  quant_fold<1, 2><<<2048, 256, 0, stream>>>(wu, wuq8, (long)I * H / 4, 6.0f, SE0W,
                                             9, 511, H / 128);
  quant_fold<1, 2><<<2048, 256, 0, stream>>>(wd, wdq8, (long)H * I / 4, 6.0f, SE0W,
                                             11, 2047, I / 128);  // K=8192

  // largest power-of-two column chunk W with S*W*4 bytes of fp32 gate fitting
  size_t avail = ws_size > base_bytes ? ws_size - base_bytes : 0;
  int W = 128;
  for (int cand = I; cand >= 128; cand >>= 1)
    if ((size_t)S * cand * 4 <= avail) { W = cand; break; }

  for (int c0 = 0; c0 < I; c0 += W) {
    int nby = W / 128;
    // gate chunk -> fp32 gatef [S][W]
    mx_gemm<0><<<32 * nby, 256, 0, stream>>>(
        xq8, H / 128, wgq8 + (size_t)c0 * H, H / 128, gatef, nullptr,
        nullptr, nullptr, W, H, W, 0, FAC_GU, 0, nby, 1);
    // up chunk + SwiGLU + fp6-MX requant (folded) -> iq8 pages, columns [c0, c0+W)
    mx_gemm<1><<<32 * nby, 256, 0, stream>>>(
        xq8, H / 128, wuq8 + (size_t)c0 * H, H / 128, nullptr, nullptr,
        gatef, iq8, W, H, I, c0, FAC_GU, SE0I, nby, 1);
  }

  // down GEMM, K split in 2 (grid 32*16*2 = 1024): ks=0 -> out, ks=1 -> pf; then add
  mx_gemm<0><<<32 * (H / 128) * 2, 256, 0, stream>>>(
      iq8, I / 128, wdq8, I / 128, out, pf, nullptr, nullptr,
      H, I / 2, H, 0, FAC_DN, 0, H / 128, 2);
  add_f32<<<2048, 256, 0, stream>>>(out, pf, (long)S * H / 4);
}

// Round 17
// 501.274 us; speedup vs baseline: 1.2973x; 1.2973x over previous
//
#include <hip/hip_runtime.h>
#include <hip/hip_bf16.h>

typedef __attribute__((ext_vector_type(4))) int i32x4;
typedef __attribute__((ext_vector_type(8))) int i32x8;
typedef __attribute__((ext_vector_type(4))) float f32x4;

// exact floor(log2(x)) for x > 0 (handles subnormals)
__device__ __forceinline__ int flog2(float x) {
  unsigned u = __float_as_uint(x);
  int e = (int)((u >> 23) & 255u);
  if (e) return e - 127;
  unsigned m = u & 0x7fffffu;
  return (31 - __clz(m)) - 149;
}

// exact 2^e for e in [-252, 254]
__device__ __forceinline__ float exp2i(int e) {
  int e1 = e >> 1, e2 = e - e1;
  return __uint_as_float((unsigned)(e1 + 127) << 23) *
         __uint_as_float((unsigned)(e2 + 127) << 23);
}

// quantize y (already divided by shared scale) to e2m<MFRAC>, round-half-even, saturate
template <int MFRAC>
__device__ __forceinline__ float qelem(float y, float maxn) {
  float ay = fabsf(y);
  int e = (ay == 0.f) ? 0 : flog2(ay);
  if (e < 0) e = 0;  // min_exp = 0 for ebits=2
  float r = rintf(y * exp2i(MFRAC - e)) * exp2i(e - MFRAC);
  return fminf(fmaxf(r, -maxn), maxn);
}

// general RNE fp32 -> OCP e4m3 encode (|v| <= 448; exact on our folded value grid)
__device__ __forceinline__ unsigned char enc_rne(float v) {
  unsigned u = __float_as_uint(v);
  unsigned s = u >> 31;
  float a = fabsf(v);
  if (a == 0.f) return (unsigned char)(s << 7);
  int e = flog2(a);
  if (e < -6) e = -6;                      // subnormal regime
  int qi = (int)rintf(a * exp2i(3 - e));   // RNE to 3-frac-bit grid -> [0,16]
  if (qi == 0) return (unsigned char)(s << 7);
  if (qi == 16) { qi = 8; e += 1; }
  unsigned exf, m;
  if (qi < 8) { exf = 0u; m = (unsigned)qi; }          // e == -6 subnormal
  else { exf = (unsigned)(e + 7); m = (unsigned)(qi - 8); }
  return (unsigned char)((s << 7) | (exf << 3) | m);
}

// fragment-page swizzle: byte address of element (row, col-in-K) in a tensor stored
// as 2KB pages per (16-row-block x 128-K-block); pa = K/128 pages per row-block.
//   byte(j*1024 + l*16 + b) = elem(row = rb*16 + (l&15), k = kb*128 + (l>>4)*32 + j*16 + b)
__device__ __forceinline__ size_t swz(int row, int col, int pa) {
  return ((size_t)((row >> 4) * pa + (col >> 7))) * 2048
       + (size_t)(((col >> 4) & 1) * 1024
       + ((row & 15) + ((col >> 5) & 3) * 16) * 16
       + (col & 15));
}

// ------ MX quantization with exponent folding -> fragment-page-swizzled e4m3 bytes ---
template <int MFRAC, int EMAX>
__global__ void quant_fold(const float* __restrict__ in, unsigned char* __restrict__ out,
                           long n4, float maxn, int se0, int kshift, int kmask, int pa) {
  long i = (long)blockIdx.x * blockDim.x + threadIdx.x;
  long stride = (long)gridDim.x * blockDim.x;
  for (; i < n4; i += stride) {
    float4 v = reinterpret_cast<const float4*>(in)[i];
    float am = fmaxf(fmaxf(fabsf(v.x), fabsf(v.y)), fmaxf(fabsf(v.z), fabsf(v.w)));
    am = fmaxf(am, __shfl_xor(am, 1));
    am = fmaxf(am, __shfl_xor(am, 2));
    am = fmaxf(am, __shfl_xor(am, 4));
    int se = ((am == 0.f) ? 0 : flog2(am)) - EMAX;
    se = se < -127 ? -127 : (se > 127 ? 127 : se);
    float inv = exp2i(-se), f = exp2i(se - se0);
    unsigned o = (unsigned)enc_rne(qelem<MFRAC>(v.x * inv, maxn) * f)
               | ((unsigned)enc_rne(qelem<MFRAC>(v.y * inv, maxn) * f) << 8)
               | ((unsigned)enc_rne(qelem<MFRAC>(v.z * inv, maxn) * f) << 16)
               | ((unsigned)enc_rne(qelem<MFRAC>(v.w * inv, maxn) * f) << 24);
    int row = (int)(i >> kshift);
    int kq = ((int)i & kmask) * 4;           // kq % 16 in {0,4,8,12}: 4B stays in-piece
    reinterpret_cast<unsigned*>(out)[swz(row, kq, pa) >> 2] = o;
  }
}

// load one MFMA fragment (lane's 32B) directly from a global fragment page
__device__ __forceinline__ i32x8 gfrag(const unsigned char* page, int l16) {
  i32x4 lo = *reinterpret_cast<const i32x4*>(page + l16);
  i32x4 hi = *reinterpret_cast<const i32x4*>(page + 1024 + l16);
  i32x8 r;
  r[0] = lo[0]; r[1] = lo[1]; r[2] = lo[2]; r[3] = lo[3];
  r[4] = hi[0]; r[5] = hi[1]; r[6] = hi[2]; r[7] = hi[3];
  return r;
}

// ----- fp8 GEMM, 16x16x128 MFMA, NO LDS / NO BARRIERS, wide wave tile 64x128 -------
// Block 128x256, 4 waves (2x2 of 64x128). Per K-step: 12 gfrag (4 A + 8 B) feed
// 32 MFMAs -> load:MFMA ratio 0.375 (vs 1.33 at 64x64); 1104 SIMD-cyc MFMA window
// hides L2 latency within the wave. Compiler-scheduled (R13 style, no manual dbuf).
// All HW scale bytes = 1.0 (0x7f7f7f7f): convention-immune, full MX instruction rate.
// EPI=0: fp32 out (+ ks split via Cf/Cf2); EPI=1: up-fused (fp32 gate in, fp8 out).
template <int EPI>
__global__ __launch_bounds__(256, 2) void mx_gemm(
    const unsigned char* __restrict__ A, int pa,
    const unsigned char* __restrict__ B, int pb,
    float* __restrict__ Cf, float* __restrict__ Cf2,
    const float* __restrict__ gate, unsigned char* __restrict__ C8,
    int W, int K, int ldC, int c0, float fac, int se0out, int nby, int nks) {
  const int t = threadIdx.x, l = t & 63, w = t >> 6;
  const int wr = w >> 1, wc = w & 1;          // 2x2 wave grid; wave tile 64x128
  const int lr16 = l & 15, lg16 = l >> 4;
  const int l16 = l * 16;
  const int n = (int)blockIdx.x;
  const int bx = n & 31, byks = n >> 5;
  const int by = byks % nby, ks = byks / nby;
  const int rowA = bx * 128, rowB = by * 256;
  const int kbs = ks * (K >> 7);               // page offset for K-split
  const int SCL = 0x7f7f7f7f;  // e8m0 1.0 in every byte: scale path is a no-op

  f32x4 acc[4][8];
#pragma unroll
  for (int i = 0; i < 4; ++i)
#pragma unroll
    for (int j = 0; j < 8; ++j) acc[i][j] = (f32x4)(0.f);

  const unsigned char* pApg[4];
  const unsigned char* pBpg[8];
#pragma unroll
  for (int m = 0; m < 4; ++m)
    pApg[m] = A + ((size_t)((rowA >> 4) + wr * 4 + m) * pa + kbs) * 2048;
#pragma unroll
  for (int nn = 0; nn < 8; ++nn)
    pBpg[nn] = B + ((size_t)((rowB >> 4) + wc * 8 + nn) * pb + kbs) * 2048;

  const int nt = K >> 7;  // 16 (gate/up) or 32 (down halves)
#pragma unroll 2
  for (int kb = 0; kb < nt; ++kb) {
    i32x8 af[4], bf[8];
#pragma unroll
    for (int m = 0; m < 4; ++m) { af[m] = gfrag(pApg[m], l16); pApg[m] += 2048; }
#pragma unroll
    for (int nn = 0; nn < 8; ++nn) { bf[nn] = gfrag(pBpg[nn], l16); pBpg[nn] += 2048; }
#pragma unroll
    for (int m = 0; m < 4; ++m)
#pragma unroll
      for (int nn = 0; nn < 8; ++nn)
        acc[m][nn] = __builtin_amdgcn_mfma_scale_f32_16x16x128_f8f6f4(
            af[m], bf[nn], acc[m][nn], 0, 0, 0, SCL, 0, SCL);
  }

  // 16x16 C/D layout: col = lane&15, row = (lane>>4)*4 + reg  (m89-verified)
  if (EPI == 0) {
    float* D = ks ? Cf2 : Cf;
#pragma unroll
    for (int m = 0; m < 4; ++m)
#pragma unroll
      for (int nn = 0; nn < 8; ++nn)
#pragma unroll
        for (int r = 0; r < 4; ++r) {
          int row = rowA + wr * 64 + m * 16 + lg16 * 4 + r;
          int col = rowB + wc * 128 + nn * 16 + lr16;
          D[(size_t)row * ldC + c0 + col] = acc[m][nn][r] * fac;
        }
  } else {
    const int pao = ldC >> 7;  // output pages per row-block
#pragma unroll
    for (int m = 0; m < 4; ++m)
#pragma unroll
      for (int p = 0; p < 4; ++p)
#pragma unroll
        for (int r = 0; r < 4; ++r) {
          int row = rowA + wr * 64 + m * 16 + lg16 * 4 + r;
          int col = rowB + wc * 128 + p * 32 + lr16;  // chunk-local column in [0, W)
          float u0 = acc[m][2 * p][r] * fac;
          float u1 = acc[m][2 * p + 1][r] * fac;
          float g0 = gate[(size_t)row * W + col];
          float g1 = gate[(size_t)row * W + col + 16];
          float v0 = u0 * (g0 / (1.f + expf(-g0)));
          float v1 = u1 * (g1 / (1.f + expf(-g1)));
          float am = fmaxf(fabsf(v0), fabsf(v1));
          am = fmaxf(am, __shfl_xor(am, 1));
          am = fmaxf(am, __shfl_xor(am, 2));
          am = fmaxf(am, __shfl_xor(am, 4));
          am = fmaxf(am, __shfl_xor(am, 8));
          int se = ((am == 0.f) ? 0 : flog2(am)) - 2;
          se = se < -127 ? -127 : (se > 127 ? 127 : se);
          float f = exp2i(-se), fo = exp2i(se - se0out);
          C8[swz(row, c0 + col, pao)] = enc_rne(qelem<3>(v0 * f, 7.5f) * fo);
          C8[swz(row, c0 + col + 16, pao)] = enc_rne(qelem<3>(v1 * f, 7.5f) * fo);
        }
  }
}

__global__ void add_f32(float* __restrict__ out, const float* __restrict__ part, long n4) {
  long i = (long)blockIdx.x * blockDim.x + threadIdx.x;
  long stride = (long)gridDim.x * blockDim.x;
  for (; i < n4; i += stride) {
    float4 a = reinterpret_cast<float4*>(out)[i];
    float4 b = reinterpret_cast<const float4*>(part)[i];
    a.x += b.x; a.y += b.y; a.z += b.z; a.w += b.w;
    reinterpret_cast<float4*>(out)[i] = a;
  }
}

extern "C" void kernel_launch(void* const* d_in, const int* in_sizes, int n_in,
                              void* d_out, int out_size, void* d_ws, size_t ws_size,
                              hipStream_t stream) {
  const float* x = (const float*)d_in[0];
  const float* wg = (const float*)d_in[1];
  const float* wu = (const float*)d_in[2];
  const float* wd = (const float*)d_in[3];
  float* out = (float*)d_out;

  const int S = 4096, H = 2048, I = 8192;

  // per-tensor fold baselines: exact while block se in [se0-6, se0+5]
  const int SE0X = -1, SE0W = -7, SE0I = -2;
  const float FAC_GU = 0.00390625f;     // 2^(SE0X + SE0W) = 2^-8
  const float FAC_DN = 0.001953125f;    // 2^(SE0I + SE0W) = 2^-9

  unsigned char* p = (unsigned char*)d_ws;
  unsigned char* xq8 = p;  p += (size_t)S * H;   //  8.4 MB (swizzled pages)
  unsigned char* wgq8 = p; p += (size_t)I * H;   // 16.8 MB
  unsigned char* wuq8 = p; p += (size_t)I * H;   // 16.8 MB
  unsigned char* wdq8 = p; p += (size_t)H * I;   // 16.8 MB
  unsigned char* iq8 = p;  p += (size_t)S * I;   // 33.6 MB
  size_t base_bytes = (size_t)(p - (unsigned char*)d_ws);  // ~92 MB
  float* gatef = (float*)p;          // chunked fp32 gate buffer (exact; feeds requant)
  float* pf = (float*)p;             // down K-split partial (reuses dead gatef)

  // quantize -> fragment-page-swizzled e4m3
  quant_fold<3, 2><<<2048, 256, 0, stream>>>(x, xq8, (long)S * H / 4, 7.5f, SE0X,
                                             9, 511, H / 128);    // K=2048
  quant_fold<1, 2><<<2048, 256, 0, stream>>>(wg, wgq8, (long)I * H / 4, 6.0f, SE0W,
                                             9, 511, H / 128);
  quant_fold<1, 2><<<2048, 256, 0, stream>>>(wu, wuq8, (long)I * H / 4, 6.0f, SE0W,
                                             9, 511, H / 128);
  quant_fold<1, 2><<<2048, 256, 0, stream>>>(wd, wdq8, (long)H * I / 4, 6.0f, SE0W,
                                             11, 2047, I / 128);  // K=8192

  // largest power-of-two column chunk W (multiple of 256) with S*W*4 fp32 gate fitting
  size_t avail = ws_size > base_bytes ? ws_size - base_bytes : 0;
  int W = 256;
  for (int cand = I; cand >= 256; cand >>= 1)
    if ((size_t)S * cand * 4 <= avail) { W = cand; break; }

  for (int c0 = 0; c0 < I; c0 += W) {
    int nby = W / 256;
    // gate chunk -> fp32 gatef [S][W]
    mx_gemm<0><<<32 * nby, 256, 0, stream>>>(
        xq8, H / 128, wgq8 + (size_t)c0 * H, H / 128, gatef, nullptr,
        nullptr, nullptr, W, H, W, 0, FAC_GU, 0, nby, 1);
    // up chunk + SwiGLU + fp6-MX requant (folded) -> iq8 pages, columns [c0, c0+W)
    mx_gemm<1><<<32 * nby, 256, 0, stream>>>(
        xq8, H / 128, wuq8 + (size_t)c0 * H, H / 128, nullptr, nullptr,
        gatef, iq8, W, H, I, c0, FAC_GU, SE0I, nby, 1);
  }

  // down GEMM, K split in 2 (grid 32*8*2 = 512): ks=0 -> out, ks=1 -> pf; then add
  mx_gemm<0><<<32 * (H / 256) * 2, 256, 0, stream>>>(
      iq8, I / 128, wdq8, I / 128, out, pf, nullptr, nullptr,
      H, I / 2, H, 0, FAC_DN, 0, H / 256, 2);
  add_f32<<<2048, 256, 0, stream>>>(out, pf, (long)S * H / 4);
}